// Round 8
// baseline (440.046 us; speedup 1.0000x reference)
//
#include <hip/hip_runtime.h>
#include <stdint.h>

// ---------- types / helpers ----------
typedef __attribute__((ext_vector_type(8))) short bf16x8;   // 8 x bf16 (4 VGPRs)
typedef __attribute__((ext_vector_type(4))) float f32x4;

__device__ __forceinline__ float bf2f(ushort u) {
  union { uint32_t u; float f; } v; v.u = ((uint32_t)u) << 16; return v.f;
}
__device__ __forceinline__ ushort f2bf(float f) {
  union { float f; uint32_t u; } v; v.f = f;
  uint32_t r = (v.u + 0x7fffu + ((v.u >> 16) & 1u)) >> 16;   // RNE
  return (ushort)r;
}

__device__ __forceinline__ f32x4 mfma16(bf16x8 a, bf16x8 b, f32x4 c) {
  return __builtin_amdgcn_mfma_f32_16x16x32_bf16(a, b, c, 0, 0, 0);
}

// async global->LDS, 16B per lane; LDS dest = wave-uniform base + lane*16
__device__ __forceinline__ void glds16(const ushort* g, ushort* l) {
  __builtin_amdgcn_global_load_lds(
      (__attribute__((address_space(1))) void*)(void*)g,
      (__attribute__((address_space(3))) void*)(void*)l, 16, 0, 0);
}

#define BAR()  __builtin_amdgcn_s_barrier()
#define LGK0() asm volatile("s_waitcnt lgkmcnt(0)" ::: "memory")
#define LGK8() asm volatile("s_waitcnt lgkmcnt(8)" ::: "memory")
#define VMC2() asm volatile("s_waitcnt vmcnt(2)" ::: "memory")
#define VMC4() asm volatile("s_waitcnt vmcnt(4)" ::: "memory")
#define VMC0() asm volatile("s_waitcnt vmcnt(0)" ::: "memory")
#define SCB0() __builtin_amdgcn_sched_barrier(0)
#define PRIO1() __builtin_amdgcn_s_setprio(1)
#define PRIO0() __builtin_amdgcn_s_setprio(0)

// ---------- elementwise cast fp32 -> bf16 (vectorized x4) ----------
__global__ __launch_bounds__(256) void cast_f32_bf16(
    const float* __restrict__ in, ushort* __restrict__ out, long n) {
  const long i = ((long)blockIdx.x * 256 + threadIdx.x) * 4;
  if (i + 3 >= n) {
    for (long j = i; j < n; j++) out[j] = f2bf(in[j]);
    return;
  }
  const float4 v = *(const float4*)&in[i];
  ushort4 o;
  o.x = f2bf(v.x); o.y = f2bf(v.y); o.z = f2bf(v.z); o.w = f2bf(v.w);
  *(ushort4*)&out[i] = o;
}

// ---------- weight transpose+cast: in fp32 [R][C] -> out bf16 [C][R] ----------
__global__ __launch_bounds__(256) void transpose_cast(
    const float* __restrict__ in, ushort* __restrict__ out, int R, int C) {
  __shared__ ushort t[32][33];
  const int tx = threadIdx.x & 31, ty = threadIdx.x >> 5;  // 32 x 8
  const int bc = blockIdx.x * 32;
  const int br = blockIdx.y * 32;
#pragma unroll
  for (int i = 0; i < 32; i += 8)
    t[ty + i][tx] = f2bf(in[(long)(br + ty + i) * C + bc + tx]);
  __syncthreads();
#pragma unroll
  for (int i = 0; i < 32; i += 8)
    out[(long)(bc + ty + i) * R + br + tx] = t[tx][ty + i];
}

// ================= 256x256 8-phase GEMM, SINGLE barrier/phase =============
// (v4, validated round 7: QKV dispatch dropped below attn_part's 113us)
// C[M][N] = A[M][K] @ Bt[N][K]^T + bias[N]
// 512 threads = 8 waves (2M x 4N), per-wave output 128x64, BK=64, NT=K/64.
// LDS 128 KiB, linear dest + pre-swizzled global source (rule #21).
// ONE barrier per phase (8/iter).  Phase order:
//   [rd (this phase's frags)][stage][BAR][lgkmcnt(0)][MFMA]
// WAR proof: a wave passes BAR(p+1) only after MFMA(p), hence after its
// lgkmcnt(0) retired ALL phase-p ds_reads.  So a stage issued in phase
// >= p+2 cannot land before every wave finished reading that region.
// vmcnt ledger (steady, entering ph1: 4 outstanding = B1@kb):
//   ph1 +A1(4) -> 8; ph4 +B0h0(2) -> 10, VMC2 retires buf1's 8;
//   ph5 +B0h1 -> 4; ph6 +A0h0 -> 6; ph7 +A0h1 -> 8;
//   ph8 +B1(4) -> 12, VMC4 retires buf0@kp0's 8; leaves 4. ✓

__device__ __forceinline__ void stg2(const ushort* src, ushort* dst, long kstride) {
  glds16(src, dst);                    // rows +0..63 of this half
  glds16(src + 64 * kstride, dst + 4096);  // rows +64..127
}

__device__ __forceinline__ void rd4(bf16x8 (&d)[4][2], const ushort* p,
                                    int kq0, int kq1) {
#pragma unroll
  for (int ii = 0; ii < 4; ii++) {
    d[ii][0] = *(const bf16x8*)&p[ii * 1024 + kq0];
    d[ii][1] = *(const bf16x8*)&p[ii * 1024 + kq1];
  }
}
__device__ __forceinline__ void rd2(bf16x8 (&d)[2][2], const ushort* p,
                                    int kq0, int kq1) {
#pragma unroll
  for (int jj = 0; jj < 2; jj++) {
    d[jj][0] = *(const bf16x8*)&p[jj * 1024 + kq0];
    d[jj][1] = *(const bf16x8*)&p[jj * 1024 + kq1];
  }
}
template <int I0, int J0>
__device__ __forceinline__ void mmq(f32x4 (&acc)[8][4], const bf16x8 (&a)[4][2],
                                    const bf16x8 (&b)[2][2]) {
#pragma unroll
  for (int ii = 0; ii < 4; ii++)
#pragma unroll
    for (int jj = 0; jj < 2; jj++)
#pragma unroll
      for (int ks = 0; ks < 2; ks++)
        acc[I0 + ii][J0 + jj] =
            mfma16(a[ii][ks], b[jj][ks], acc[I0 + ii][J0 + jj]);
}

template <bool F32OUT>
__global__ __launch_bounds__(512, 2) void gemm256(
    const ushort* __restrict__ A, const ushort* __restrict__ Bt,
    const float* __restrict__ bias, void* __restrict__ Cout,
    int N, int K, int NBM) {
  __shared__ ushort lds[2][2][16384];
  const int tid = threadIdx.x;
  const int wave = tid >> 6, lane = tid & 63;
  const int quad = lane >> 4, l16 = lane & 15;
  const int wm = wave >> 2, wn = wave & 3;   // 2 x 4 wave grid
  const long Kl = K;

  // T1: bijective XCD swizzle (grid % 8 == 0 for both call sites)
  const int nwg = gridDim.x;
  const int wg = ((int)blockIdx.x & 7) * (nwg >> 3) + ((int)blockIdx.x >> 3);
  const int bm = (wg % NBM) * 256;
  const int bn = (wg / NBM) * 256;
  const int NT = K >> 6;

  // Staging source map (read-swizzle inverse applied to global addr):
  //   row_in_64 = wave*8 + lane/8,  col16 = (lane&7) ^ (lane>>3 & 7)
  const int srow = (wave << 3) + (lane >> 3);
  const int kc8 = ((lane & 7) ^ ((lane >> 3) & 7)) << 3;
  const ushort* Asrc = A + (long)(bm + srow) * Kl + kc8;
  const ushort* Bsrc = Bt + (long)(bn + srow) * Kl + kc8;

#define STAGE(SRC, BUF, MAT, H, KT)                                       \
  stg2(SRC + (long)(H) * 128 * Kl + (long)(KT) * 64,                      \
       &lds[BUF][MAT][(H) * 8192 + (wave << 9)], Kl)

  // Read-side swizzled k-offsets: elem (r, ks*32+quad*8), group ^ (r&7);
  // r&7 == l16&7 for every fragment row of this lane.
  const int kq0 = (quad ^ (l16 & 7)) << 3;
  const int kq1 = ((4 | quad) ^ (l16 & 7)) << 3;

  f32x4 acc[8][4] = {};

  // prologue: buf0 full @0, buf1-B @1 (buf1-A comes JIT at ph1).
  STAGE(Bsrc, 0, 1, 0, 0); STAGE(Bsrc, 0, 1, 1, 0);
  STAGE(Asrc, 0, 0, 0, 0); STAGE(Asrc, 0, 0, 1, 0);
  STAGE(Bsrc, 1, 1, 0, 1); STAGE(Bsrc, 1, 1, 1, 1);
  VMC4(); BAR();

  const int NI = NT >> 1;
#pragma unroll 1
  for (int t = 0; t < NI; ++t) {
    const int kb  = 2 * t + 1;
    const int kp0 = (2 * t + 2 < NT) ? 2 * t + 2 : NT - 1;  // clamp: same-data reload
    const int kp1 = (2 * t + 3 < NT) ? 2 * t + 3 : NT - 1;
    bf16x8 a[4][2], b0[2][2], b1[2][2];

    // ---- ph1: rd buf0 A-lo(8)+B-lo(4); stage buf1-A both halves @kb
    rd4(a, &lds[0][0][(wm * 128 + l16) * 64], kq0, kq1);
    rd2(b0, &lds[0][1][(wn * 64 + l16) * 64], kq0, kq1);
    STAGE(Asrc, 1, 0, 0, kb);
    STAGE(Asrc, 1, 0, 1, kb);
    LGK8();
    BAR(); LGK0(); SCB0();
    PRIO1(); mmq<0, 0>(acc, a, b0); PRIO0();

    // ---- ph2: rd buf0 B-hi(4)
    rd2(b1, &lds[0][1][(wn * 64 + 32 + l16) * 64], kq0, kq1);
    BAR(); LGK0(); SCB0();
    PRIO1(); mmq<0, 2>(acc, a, b1); PRIO0();

    // ---- ph3: rd buf0 A-hi(8)
    rd4(a, &lds[0][0][(wm * 128 + 64 + l16) * 64], kq0, kq1);
    BAR(); LGK0(); SCB0();
    PRIO1(); mmq<4, 0>(acc, a, b0); PRIO0();

    // ---- ph4: stage B0h0@kp0; VMC2 retires buf1 (A+B) before ph5 reads
    STAGE(Bsrc, 0, 1, 0, kp0);
    VMC2();
    BAR();
    PRIO1(); mmq<4, 2>(acc, a, b1); PRIO0();

    // ---- ph5: rd buf1 A-lo(8)+B-lo(4); stage B0h1@kp0
    rd4(a, &lds[1][0][(wm * 128 + l16) * 64], kq0, kq1);
    rd2(b0, &lds[1][1][(wn * 64 + l16) * 64], kq0, kq1);
    STAGE(Bsrc, 0, 1, 1, kp0);
    LGK8();
    BAR(); LGK0(); SCB0();
    PRIO1(); mmq<0, 0>(acc, a, b0); PRIO0();

    // ---- ph6: rd buf1 B-hi(4); stage A0h0@kp0
    rd2(b1, &lds[1][1][(wn * 64 + 32 + l16) * 64], kq0, kq1);
    STAGE(Asrc, 0, 0, 0, kp0);
    BAR(); LGK0(); SCB0();
    PRIO1(); mmq<0, 2>(acc, a, b1); PRIO0();

    // ---- ph7: rd buf1 A-hi(8); stage A0h1@kp0
    rd4(a, &lds[1][0][(wm * 128 + 64 + l16) * 64], kq0, kq1);
    STAGE(Asrc, 0, 0, 1, kp0);
    BAR(); LGK0(); SCB0();
    PRIO1(); mmq<4, 0>(acc, a, b0); PRIO0();

    // ---- ph8: stage buf1-B both halves @kp1; VMC4 retires buf0@kp0
    STAGE(Bsrc, 1, 1, 0, kp1);
    STAGE(Bsrc, 1, 1, 1, kp1);
    VMC4();
    BAR();
    PRIO1(); mmq<4, 2>(acc, a, b1); PRIO0();
  }
  VMC0();  // drain tail prefetches before epilogue/endpgm

  // epilogue: C row = bm + wm*128 + i*16 + quad*4 + r, col = bn + wn*64 + j*16 + l16
#pragma unroll
  for (int i = 0; i < 8; i++) {
#pragma unroll
    for (int j = 0; j < 4; j++) {
      const int col = bn + wn * 64 + j * 16 + l16;
      const float bv = bias[col];
#pragma unroll
      for (int r = 0; r < 4; r++) {
        const int row = bm + wm * 128 + i * 16 + quad * 4 + r;
        const float v = acc[i][j][r] + bv;
        if (F32OUT)
          ((float*)Cout)[(long)row * N + col] = v;
        else
          ((ushort*)Cout)[(long)row * N + col] = f2bf(v);
      }
    }
  }
#undef STAGE
}

// ---------- RoPE ----------
__global__ __launch_bounds__(256) void rope_table(float* __restrict__ tab) {
  const int i = blockIdx.x * 256 + threadIdx.x;  // 2048*64
  const int d = i & 63, s = i >> 6;
  const float f = powf(10000.0f, -(float)(2 * d) / 128.0f);
  const float ang = (float)s * f;
  tab[i] = cosf(ang);
  tab[131072 + i] = sinf(ang);
}

// vectorized: 8 d-elements per thread, uint4 r/w (G13)
__global__ __launch_bounds__(256) void rope_apply(ushort* __restrict__ qkv,
                                                  const float* __restrict__ tab) {
  const int i = blockIdx.x * 256 + threadIdx.x;  // B*S*H*8 = 524288
  const int d8 = (i & 7) * 8;                    // 0..56
  const int h = (i >> 3) & 15;
  const long bs = i >> 7;                        // b*2048 + s
  const int s = (int)(bs & 2047);
  const float* ct = &tab[(s << 6) + d8];
  const float* st = &tab[131072 + (s << 6) + d8];
  float c[8], sn[8];
  *(float4*)&c[0] = *(const float4*)&ct[0];
  *(float4*)&c[4] = *(const float4*)&ct[4];
  *(float4*)&sn[0] = *(const float4*)&st[0];
  *(float4*)&sn[4] = *(const float4*)&st[4];
  ushort* row = qkv + bs * 6144 + h * 128 + d8;
#pragma unroll
  for (int qk = 0; qk < 2; qk++) {
    ushort* p = row + qk * 2048;
    ushort x1[8] __attribute__((aligned(16)));
    ushort x2[8] __attribute__((aligned(16)));
    *(uint4*)x1 = *(const uint4*)p;
    *(uint4*)x2 = *(const uint4*)(p + 64);
#pragma unroll
    for (int e = 0; e < 8; e++) {
      const float a = bf2f(x1[e]), b2 = bf2f(x2[e]);
      x1[e] = f2bf(a * c[e] - b2 * sn[e]);
      x2[e] = f2bf(b2 * c[e] + a * sn[e]);
    }
    *(uint4*)p = *(uint4*)x1;
    *(uint4*)(p + 64) = *(uint4*)x2;
  }
}

// ---------- flash attention, KV-split partial kernel ----------
// Unnormalized-exp: partial o and l over disjoint KV chunks combine by pure
// addition. Block = (qt, chunk) x (h, b); <=T iterations of 64 keys each.
// blockIdx.x enumerates (qt desc, chunk) so big blocks dispatch first.
// NEW (round 8): L2 warm-up prefetch — during tile i's compute, each of the
// 256 threads touches one 64B line of tile i+1's K and V (512 lines = the
// whole 32KB next tile), so next iteration's staging loads hit L2 instead
// of L3/HBM.  No registers held across iterations (rule-20-safe), no LDS
// growth, occupancy unchanged at 3 blocks/CU.
#define KSTR 136
#define VSTR 68
__global__ __launch_bounds__(256) void attn_part(
    const ushort* __restrict__ qkv, float* __restrict__ part_o,
    float* __restrict__ part_l, int T, int slots_bh) {
  const int S = 2048, LD = 6144;
  const int tid = threadIdx.x;
  const int wave = tid >> 6, lane = tid & 63;
  const int quad = lane >> 4, l16 = lane & 15;
  const int h = blockIdx.y;
  const int b = blockIdx.z;

  // decode (qt, chunk) from blockIdx.x, qt descending
  int y = blockIdx.x, qt = -1, ch = 0;
  for (int q = 31; q >= 0; --q) {
    const int c = q / T + 1;
    if (qt < 0) {
      if (y < c) { qt = q; ch = y; } else y -= c;
    }
  }
  int sb = 0;
  for (int q = 0; q < qt; q++) sb += q / T + 1;
  const long slot = ((long)(b * 16 + h)) * slots_bh + sb + ch;

  const ushort* base = qkv + (long)b * S * LD;
  const int qrow0 = qt * 64 + wave * 16;
  const int kb0 = ch * T * 64;
  const int kbend = min((ch + 1) * T * 64, qt * 64 + 64);

  __shared__ ushort Ks[64 * KSTR];
  __shared__ ushort Vs[128 * VSTR];
  __shared__ ushort Ps[4][16 * VSTR];

  // Q fragments (A-layout)
  bf16x8 qf[4];
  {
    const ushort* qp = base + (long)(qrow0 + l16) * LD + h * 128 + quad * 8;
#pragma unroll
    for (int c = 0; c < 4; c++) qf[c] = *(const bf16x8*)(qp + c * 32);
  }

  float l_lane[4] = {0.f, 0.f, 0.f, 0.f};
  f32x4 o[8];
#pragma unroll
  for (int f = 0; f < 8; f++) o[f] = (f32x4){0.f, 0.f, 0.f, 0.f};

  const float scale = 0.08838834764831845f;  // 1/sqrt(128)

  // staging maps
  const int k_row = tid >> 4;
  const int k_dcol = (tid & 15) * 8;
  const int v_key2 = (tid & 31) * 2;
  const int v_dc0 = tid >> 5;
  // prefetch map: row = tid>>2 (0..63), 64B segment = tid&3
  const long pf_off = (long)(tid >> 2) * LD + h * 128 + (tid & 3) * 32;

  for (int kb = kb0; kb < kbend; kb += 64) {
    __syncthreads();   // prior-iter LDS reads done
    // stage K [64][128]
#pragma unroll
    for (int it = 0; it < 4; it++) {
      const int row = k_row + it * 16;
      *(uint4*)&Ks[row * KSTR + k_dcol] =
          *(const uint4*)(base + (long)(kb + row) * LD + 2048 + h * 128 + k_dcol);
    }
    // stage V transposed [d][key], packed pair writes
#pragma unroll
    for (int it = 0; it < 2; it++) {
      const int dc = v_dc0 + it * 8;
      const ushort* vg = base + (long)(kb + v_key2) * LD + 4096 + h * 128 + dc * 8;
      ushort va[8] __attribute__((aligned(16)));
      ushort vb[8] __attribute__((aligned(16)));
      *(uint4*)va = *(const uint4*)vg;
      *(uint4*)vb = *(const uint4*)(vg + LD);
#pragma unroll
      for (int e = 0; e < 8; e++) {
        const uint32_t pk = (uint32_t)va[e] | ((uint32_t)vb[e] << 16);
        *(uint32_t*)&Vs[(dc * 8 + e) * VSTR + v_key2] = pk;
      }
    }
    __syncthreads();

    // L2 warm-up prefetch of next tile's K and V cache lines; results are
    // sunk (kept live, unused) so latency hides under the compute below.
    if (kb + 64 < kbend) {
      const ushort* pk = base + (long)(kb + 64) * LD + 2048 + pf_off;
      uint32_t t0 = *(const volatile uint32_t*)pk;
      uint32_t t1 = *(const volatile uint32_t*)(pk + 2048);
      asm volatile("" :: "v"(t0), "v"(t1));
    }

    // wave-uniform live sub-tile count (diagonal tile only)
    int nkt = (qrow0 + 15 - kb) / 16 + 1;
    if (nkt > 4) nkt = 4;

    // S = Q K^T
    f32x4 sc[4] = {};
#pragma unroll
    for (int kt = 0; kt < 4; kt++) {
      if (kt < nkt) {
#pragma unroll
        for (int c = 0; c < 4; c++) {
          bf16x8 kf = *(const bf16x8*)&Ks[(kt * 16 + l16) * KSTR + c * 32 + quad * 8];
          sc[kt] = mfma16(qf[c], kf, sc[kt]);
        }
      }
    }

    // unnormalized exp + causal mask
#pragma unroll
    for (int r = 0; r < 4; r++) {
      const int qpos = qrow0 + quad * 4 + r;
      const int prow = (quad * 4 + r) * VSTR;
      float psum = 0.f;
#pragma unroll
      for (int kt = 0; kt < 4; kt++) {
        const float e = __expf(sc[kt][r] * scale);
        const float p = (kb + kt * 16 + l16 > qpos) ? 0.f : e;
        psum += p;
        Ps[wave][prow + kt * 16 + l16] = f2bf(p);
      }
      l_lane[r] += psum;
    }

    // PV
    bf16x8 pf0 = *(const bf16x8*)&Ps[wave][l16 * VSTR + quad * 8];
#pragma unroll
    for (int f = 0; f < 8; f++) {
      bf16x8 vf0 = *(const bf16x8*)&Vs[(f * 16 + l16) * VSTR + quad * 8];
      o[f] = mfma16(pf0, vf0, o[f]);
    }
    if (nkt > 2) {
      bf16x8 pf1 = *(const bf16x8*)&Ps[wave][l16 * VSTR + 32 + quad * 8];
#pragma unroll
      for (int f = 0; f < 8; f++) {
        bf16x8 vf1 = *(const bf16x8*)&Vs[(f * 16 + l16) * VSTR + 32 + quad * 8];
        o[f] = mfma16(pf1, vf1, o[f]);
      }
    }
  }

  // write partials: o rows are wave*16 + quad*4 + r, cols f*16+l16
  float* po = part_o + slot * 8192;
#pragma unroll
  for (int r = 0; r < 4; r++) {
    float l = l_lane[r];
    l += __shfl_xor(l, 1);
    l += __shfl_xor(l, 2);
    l += __shfl_xor(l, 4);
    l += __shfl_xor(l, 8);
    const int row = wave * 16 + quad * 4 + r;
#pragma unroll
    for (int f = 0; f < 8; f++)
      po[row * 128 + f * 16 + l16] = o[f][r];
    if (l16 == 0) part_l[slot * 64 + row] = l;
  }
}

// ---------- merge partials -> attnb (bf16) ----------
__global__ __launch_bounds__(256) void attn_merge(
    const float* __restrict__ part_o, const float* __restrict__ part_l,
    ushort* __restrict__ attnb, int T, int slots_bh) {
  const int qt = blockIdx.x, h = blockIdx.y, b = blockIdx.z;
  const int tid = threadIdx.x;
  const int cnt = qt / T + 1;
  int sb = 0;
  for (int q = 0; q < qt; q++) sb += q / T + 1;
  const long slot0 = ((long)(b * 16 + h)) * slots_bh + sb;

  for (int e4 = tid; e4 < 2048; e4 += 256) {   // float4 index within 64x128
    const int elem = e4 * 4;
    const int row = elem >> 7;
    const int d = elem & 127;
    float4 s = {0.f, 0.f, 0.f, 0.f};
    float l = 0.f;
    for (int c = 0; c < cnt; c++) {
      const float4 p = *(const float4*)&part_o[(slot0 + c) * 8192 + elem];
      s.x += p.x; s.y += p.y; s.z += p.z; s.w += p.w;
      l += part_l[(slot0 + c) * 64 + row];
    }
    const float inv = 1.0f / l;
    ushort4 ov;
    ov.x = f2bf(s.x * inv); ov.y = f2bf(s.y * inv);
    ov.z = f2bf(s.z * inv); ov.w = f2bf(s.w * inv);
    *(ushort4*)&attnb[((long)b * 2048 + qt * 64 + row) * 2048 + h * 128 + d] = ov;
  }
}

// ---------- launch ----------
static const void* find_by_size(void* const* d_in, const int* in_sizes,
                                int n_in, long want) {
  for (int i = 0; i < n_in; i++)
    if ((long)in_sizes[i] == want) return d_in[i];
  return nullptr;
}

extern "C" void kernel_launch(void* const* d_in, const int* in_sizes, int n_in,
                              void* d_out, int out_size, void* d_ws, size_t ws_size,
                              hipStream_t stream) {
  const float* hidden = (const float*)find_by_size(d_in, in_sizes, n_in, 8388608);
  const float* Wqkv   = (const float*)find_by_size(d_in, in_sizes, n_in, 12582912);
  const float* bqkv   = (const float*)find_by_size(d_in, in_sizes, n_in, 6144);
  const float* Wo     = (const float*)find_by_size(d_in, in_sizes, n_in, 4194304);
  const float* bo     = (const float*)find_by_size(d_in, in_sizes, n_in, 2048);

  uintptr_t w = (uintptr_t)d_ws;
  ushort* hiddenB = (ushort*)w; w += (size_t)4096 * 2048 * 2;
  ushort* WqkvT   = (ushort*)w; w += (size_t)6144 * 2048 * 2;
  ushort* WoT     = (ushort*)w; w += (size_t)2048 * 2048 * 2;
  ushort* qkvb    = (ushort*)w; w += (size_t)4096 * 6144 * 2;
  ushort* attnb   = (ushort*)w; w += (size_t)4096 * 2048 * 2;
  float*  tab     = (float*)w;  w += (size_t)2048 * 64 * 2 * 4;
  const size_t fixed_bytes = w - (uintptr_t)d_ws;

  // choose T (iters of 64 keys per attn block): smallest that fits ws
  int T = 8, slots_bh = 0;
  for (;; T *= 2) {
    slots_bh = 0;
    for (int q = 0; q < 32; q++) slots_bh += q / T + 1;
    const size_t need = fixed_bytes +
        (size_t)slots_bh * 32 * (8192 + 64) * 4;
    if (need <= ws_size || T >= 32) break;
  }
  float* part_o = (float*)w; w += (size_t)slots_bh * 32 * 8192 * 4;
  float* part_l = (float*)w; w += (size_t)slots_bh * 32 * 64 * 4;

  cast_f32_bf16<<<8192, 256, 0, stream>>>(hidden, hiddenB, 8388608L);
  transpose_cast<<<dim3(192, 64), 256, 0, stream>>>(Wqkv, WqkvT, 2048, 6144);
  transpose_cast<<<dim3(64, 64), 256, 0, stream>>>(Wo, WoT, 2048, 2048);
  rope_table<<<512, 256, 0, stream>>>(tab);
  // QKV: M=4096 N=6144 K=2048 -> 16x24 = 384 blocks (384%8==0)
  gemm256<false><<<dim3(384), 512, 0, stream>>>(hiddenB, WqkvT, bqkv,
                                                qkvb, 6144, 2048, 16);
  rope_apply<<<2048, 256, 0, stream>>>(qkvb, tab);
  attn_part<<<dim3(slots_bh, 16, 2), 256, 0, stream>>>(qkvb, part_o, part_l,
                                                       T, slots_bh);
  attn_merge<<<dim3(32, 16, 2), 256, 0, stream>>>(part_o, part_l, attnb,
                                                  T, slots_bh);
  // proj: M=4096 N=2048 K=2048 -> 16x8 = 128 blocks (128%8==0)
  gemm256<true><<<dim3(128), 512, 0, stream>>>(attnb, WoT, bo,
                                               d_out, 2048, 2048, 16);
}

// Round 9
// 416.315 us; speedup vs baseline: 1.0570x; 1.0570x over previous
//
#include <hip/hip_runtime.h>
#include <stdint.h>

// ---------- types / helpers ----------
typedef __attribute__((ext_vector_type(8))) short bf16x8;   // 8 x bf16 (4 VGPRs)
typedef __attribute__((ext_vector_type(4))) float f32x4;

__device__ __forceinline__ float bf2f(ushort u) {
  union { uint32_t u; float f; } v; v.u = ((uint32_t)u) << 16; return v.f;
}
__device__ __forceinline__ ushort f2bf(float f) {
  union { float f; uint32_t u; } v; v.f = f;
  uint32_t r = (v.u + 0x7fffu + ((v.u >> 16) & 1u)) >> 16;   // RNE
  return (ushort)r;
}

__device__ __forceinline__ f32x4 mfma16(bf16x8 a, bf16x8 b, f32x4 c) {
  return __builtin_amdgcn_mfma_f32_16x16x32_bf16(a, b, c, 0, 0, 0);
}

// async global->LDS, 16B per lane; LDS dest = wave-uniform base + lane*16
__device__ __forceinline__ void glds16(const ushort* g, ushort* l) {
  __builtin_amdgcn_global_load_lds(
      (__attribute__((address_space(1))) void*)(void*)g,
      (__attribute__((address_space(3))) void*)(void*)l, 16, 0, 0);
}

#define BAR()  __builtin_amdgcn_s_barrier()
#define LGK0() asm volatile("s_waitcnt lgkmcnt(0)" ::: "memory")
#define LGK8() asm volatile("s_waitcnt lgkmcnt(8)" ::: "memory")
#define VMC2() asm volatile("s_waitcnt vmcnt(2)" ::: "memory")
#define VMC4() asm volatile("s_waitcnt vmcnt(4)" ::: "memory")
#define VMC0() asm volatile("s_waitcnt vmcnt(0)" ::: "memory")
#define SCB0() __builtin_amdgcn_sched_barrier(0)
#define PRIO1() __builtin_amdgcn_s_setprio(1)
#define PRIO0() __builtin_amdgcn_s_setprio(0)

// ---------- elementwise cast fp32 -> bf16 (vectorized x4) ----------
__global__ __launch_bounds__(256) void cast_f32_bf16(
    const float* __restrict__ in, ushort* __restrict__ out, long n) {
  const long i = ((long)blockIdx.x * 256 + threadIdx.x) * 4;
  if (i + 3 >= n) {
    for (long j = i; j < n; j++) out[j] = f2bf(in[j]);
    return;
  }
  const float4 v = *(const float4*)&in[i];
  ushort4 o;
  o.x = f2bf(v.x); o.y = f2bf(v.y); o.z = f2bf(v.z); o.w = f2bf(v.w);
  *(ushort4*)&out[i] = o;
}

// ---------- weight transpose+cast: in fp32 [R][C] -> out bf16 [C][R] ----------
__global__ __launch_bounds__(256) void transpose_cast(
    const float* __restrict__ in, ushort* __restrict__ out, int R, int C) {
  __shared__ ushort t[32][33];
  const int tx = threadIdx.x & 31, ty = threadIdx.x >> 5;  // 32 x 8
  const int bc = blockIdx.x * 32;
  const int br = blockIdx.y * 32;
#pragma unroll
  for (int i = 0; i < 32; i += 8)
    t[ty + i][tx] = f2bf(in[(long)(br + ty + i) * C + bc + tx]);
  __syncthreads();
#pragma unroll
  for (int i = 0; i < 32; i += 8)
    out[(long)(bc + ty + i) * R + br + tx] = t[tx][ty + i];
}

// ================= 256x256 8-phase GEMM, SINGLE barrier/phase =============
// (v4, validated round 7: QKV dispatch dropped below attn_part)
// C[M][N] = A[M][K] @ Bt[N][K]^T + bias[N]
// 512 threads = 8 waves (2M x 4N), per-wave output 128x64, BK=64, NT=K/64.
// LDS 128 KiB, linear dest + pre-swizzled global source (rule #21).
// ONE barrier per phase (8/iter).  Phase order:
//   [rd (this phase's frags)][stage][BAR][lgkmcnt(0)][MFMA]
// WAR proof: a wave passes BAR(p+1) only after MFMA(p), hence after its
// lgkmcnt(0) retired ALL phase-p ds_reads.  So a stage issued in phase
// >= p+2 cannot land before every wave finished reading that region.
// vmcnt ledger (steady, entering ph1: 4 outstanding = B1@kb):
//   ph1 +A1(4) -> 8; ph4 +B0h0(2) -> 10, VMC2 retires buf1's 8;
//   ph5 +B0h1 -> 4; ph6 +A0h0 -> 6; ph7 +A0h1 -> 8;
//   ph8 +B1(4) -> 12, VMC4 retires buf0@kp0's 8; leaves 4. ✓

__device__ __forceinline__ void stg2(const ushort* src, ushort* dst, long kstride) {
  glds16(src, dst);                    // rows +0..63 of this half
  glds16(src + 64 * kstride, dst + 4096);  // rows +64..127
}

__device__ __forceinline__ void rd4(bf16x8 (&d)[4][2], const ushort* p,
                                    int kq0, int kq1) {
#pragma unroll
  for (int ii = 0; ii < 4; ii++) {
    d[ii][0] = *(const bf16x8*)&p[ii * 1024 + kq0];
    d[ii][1] = *(const bf16x8*)&p[ii * 1024 + kq1];
  }
}
__device__ __forceinline__ void rd2(bf16x8 (&d)[2][2], const ushort* p,
                                    int kq0, int kq1) {
#pragma unroll
  for (int jj = 0; jj < 2; jj++) {
    d[jj][0] = *(const bf16x8*)&p[jj * 1024 + kq0];
    d[jj][1] = *(const bf16x8*)&p[jj * 1024 + kq1];
  }
}
template <int I0, int J0>
__device__ __forceinline__ void mmq(f32x4 (&acc)[8][4], const bf16x8 (&a)[4][2],
                                    const bf16x8 (&b)[2][2]) {
#pragma unroll
  for (int ii = 0; ii < 4; ii++)
#pragma unroll
    for (int jj = 0; jj < 2; jj++)
#pragma unroll
      for (int ks = 0; ks < 2; ks++)
        acc[I0 + ii][J0 + jj] =
            mfma16(a[ii][ks], b[jj][ks], acc[I0 + ii][J0 + jj]);
}

template <bool F32OUT>
__global__ __launch_bounds__(512, 2) void gemm256(
    const ushort* __restrict__ A, const ushort* __restrict__ Bt,
    const float* __restrict__ bias, void* __restrict__ Cout,
    int N, int K, int NBM) {
  __shared__ ushort lds[2][2][16384];
  const int tid = threadIdx.x;
  const int wave = tid >> 6, lane = tid & 63;
  const int quad = lane >> 4, l16 = lane & 15;
  const int wm = wave >> 2, wn = wave & 3;   // 2 x 4 wave grid
  const long Kl = K;

  // T1: bijective XCD swizzle (grid % 8 == 0 for both call sites)
  const int nwg = gridDim.x;
  const int wg = ((int)blockIdx.x & 7) * (nwg >> 3) + ((int)blockIdx.x >> 3);
  const int bm = (wg % NBM) * 256;
  const int bn = (wg / NBM) * 256;
  const int NT = K >> 6;

  // Staging source map (read-swizzle inverse applied to global addr):
  //   row_in_64 = wave*8 + lane/8,  col16 = (lane&7) ^ (lane>>3 & 7)
  const int srow = (wave << 3) + (lane >> 3);
  const int kc8 = ((lane & 7) ^ ((lane >> 3) & 7)) << 3;
  const ushort* Asrc = A + (long)(bm + srow) * Kl + kc8;
  const ushort* Bsrc = Bt + (long)(bn + srow) * Kl + kc8;

#define STAGE(SRC, BUF, MAT, H, KT)                                       \
  stg2(SRC + (long)(H) * 128 * Kl + (long)(KT) * 64,                      \
       &lds[BUF][MAT][(H) * 8192 + (wave << 9)], Kl)

  // Read-side swizzled k-offsets: elem (r, ks*32+quad*8), group ^ (r&7);
  // r&7 == l16&7 for every fragment row of this lane.
  const int kq0 = (quad ^ (l16 & 7)) << 3;
  const int kq1 = ((4 | quad) ^ (l16 & 7)) << 3;

  f32x4 acc[8][4] = {};

  // prologue: buf0 full @0, buf1-B @1 (buf1-A comes JIT at ph1).
  STAGE(Bsrc, 0, 1, 0, 0); STAGE(Bsrc, 0, 1, 1, 0);
  STAGE(Asrc, 0, 0, 0, 0); STAGE(Asrc, 0, 0, 1, 0);
  STAGE(Bsrc, 1, 1, 0, 1); STAGE(Bsrc, 1, 1, 1, 1);
  VMC4(); BAR();

  const int NI = NT >> 1;
#pragma unroll 1
  for (int t = 0; t < NI; ++t) {
    const int kb  = 2 * t + 1;
    const int kp0 = (2 * t + 2 < NT) ? 2 * t + 2 : NT - 1;  // clamp: same-data reload
    const int kp1 = (2 * t + 3 < NT) ? 2 * t + 3 : NT - 1;
    bf16x8 a[4][2], b0[2][2], b1[2][2];

    // ---- ph1: rd buf0 A-lo(8)+B-lo(4); stage buf1-A both halves @kb
    rd4(a, &lds[0][0][(wm * 128 + l16) * 64], kq0, kq1);
    rd2(b0, &lds[0][1][(wn * 64 + l16) * 64], kq0, kq1);
    STAGE(Asrc, 1, 0, 0, kb);
    STAGE(Asrc, 1, 0, 1, kb);
    LGK8();
    BAR(); LGK0(); SCB0();
    PRIO1(); mmq<0, 0>(acc, a, b0); PRIO0();

    // ---- ph2: rd buf0 B-hi(4)
    rd2(b1, &lds[0][1][(wn * 64 + 32 + l16) * 64], kq0, kq1);
    BAR(); LGK0(); SCB0();
    PRIO1(); mmq<0, 2>(acc, a, b1); PRIO0();

    // ---- ph3: rd buf0 A-hi(8)
    rd4(a, &lds[0][0][(wm * 128 + 64 + l16) * 64], kq0, kq1);
    BAR(); LGK0(); SCB0();
    PRIO1(); mmq<4, 0>(acc, a, b0); PRIO0();

    // ---- ph4: stage B0h0@kp0; VMC2 retires buf1 (A+B) before ph5 reads
    STAGE(Bsrc, 0, 1, 0, kp0);
    VMC2();
    BAR();
    PRIO1(); mmq<4, 2>(acc, a, b1); PRIO0();

    // ---- ph5: rd buf1 A-lo(8)+B-lo(4); stage B0h1@kp0
    rd4(a, &lds[1][0][(wm * 128 + l16) * 64], kq0, kq1);
    rd2(b0, &lds[1][1][(wn * 64 + l16) * 64], kq0, kq1);
    STAGE(Bsrc, 0, 1, 1, kp0);
    LGK8();
    BAR(); LGK0(); SCB0();
    PRIO1(); mmq<0, 0>(acc, a, b0); PRIO0();

    // ---- ph6: rd buf1 B-hi(4); stage A0h0@kp0
    rd2(b1, &lds[1][1][(wn * 64 + 32 + l16) * 64], kq0, kq1);
    STAGE(Asrc, 0, 0, 0, kp0);
    BAR(); LGK0(); SCB0();
    PRIO1(); mmq<0, 2>(acc, a, b1); PRIO0();

    // ---- ph7: rd buf1 A-hi(8); stage A0h1@kp0
    rd4(a, &lds[1][0][(wm * 128 + 64 + l16) * 64], kq0, kq1);
    STAGE(Asrc, 0, 0, 1, kp0);
    BAR(); LGK0(); SCB0();
    PRIO1(); mmq<4, 0>(acc, a, b0); PRIO0();

    // ---- ph8: stage buf1-B both halves @kp1; VMC4 retires buf0@kp0
    STAGE(Bsrc, 1, 1, 0, kp1);
    STAGE(Bsrc, 1, 1, 1, kp1);
    VMC4();
    BAR();
    PRIO1(); mmq<4, 2>(acc, a, b1); PRIO0();
  }
  VMC0();  // drain tail prefetches before epilogue/endpgm

  // epilogue: C row = bm + wm*128 + i*16 + quad*4 + r, col = bn + wn*64 + j*16 + l16
#pragma unroll
  for (int i = 0; i < 8; i++) {
#pragma unroll
    for (int j = 0; j < 4; j++) {
      const int col = bn + wn * 64 + j * 16 + l16;
      const float bv = bias[col];
#pragma unroll
      for (int r = 0; r < 4; r++) {
        const int row = bm + wm * 128 + i * 16 + quad * 4 + r;
        const float v = acc[i][j][r] + bv;
        if (F32OUT)
          ((float*)Cout)[(long)row * N + col] = v;
        else
          ((ushort*)Cout)[(long)row * N + col] = f2bf(v);
      }
    }
  }
#undef STAGE
}

// ---------- RoPE ----------
__global__ __launch_bounds__(256) void rope_table(float* __restrict__ tab) {
  const int i = blockIdx.x * 256 + threadIdx.x;  // 2048*64
  const int d = i & 63, s = i >> 6;
  const float f = powf(10000.0f, -(float)(2 * d) / 128.0f);
  const float ang = (float)s * f;
  tab[i] = cosf(ang);
  tab[131072 + i] = sinf(ang);
}

// vectorized: 8 d-elements per thread, uint4 r/w (G13)
__global__ __launch_bounds__(256) void rope_apply(ushort* __restrict__ qkv,
                                                  const float* __restrict__ tab) {
  const int i = blockIdx.x * 256 + threadIdx.x;  // B*S*H*8 = 524288
  const int d8 = (i & 7) * 8;                    // 0..56
  const int h = (i >> 3) & 15;
  const long bs = i >> 7;                        // b*2048 + s
  const int s = (int)(bs & 2047);
  const float* ct = &tab[(s << 6) + d8];
  const float* st = &tab[131072 + (s << 6) + d8];
  float c[8], sn[8];
  *(float4*)&c[0] = *(const float4*)&ct[0];
  *(float4*)&c[4] = *(const float4*)&ct[4];
  *(float4*)&sn[0] = *(const float4*)&st[0];
  *(float4*)&sn[4] = *(const float4*)&st[4];
  ushort* row = qkv + bs * 6144 + h * 128 + d8;
#pragma unroll
  for (int qk = 0; qk < 2; qk++) {
    ushort* p = row + qk * 2048;
    ushort x1[8] __attribute__((aligned(16)));
    ushort x2[8] __attribute__((aligned(16)));
    *(uint4*)x1 = *(const uint4*)p;
    *(uint4*)x2 = *(const uint4*)(p + 64);
#pragma unroll
    for (int e = 0; e < 8; e++) {
      const float a = bf2f(x1[e]), b2 = bf2f(x2[e]);
      x1[e] = f2bf(a * c[e] - b2 * sn[e]);
      x2[e] = f2bf(b2 * c[e] + a * sn[e]);
    }
    *(uint4*)p = *(uint4*)x1;
    *(uint4*)(p + 64) = *(uint4*)x2;
  }
}

// ---------- flash attention, KV-split partial kernel (QBLK=128) ----------
// Round 9: Q-tile doubled to 128 rows / 8 waves / 512 threads.  Halves the
// K/V staging count (272 vs 528 tiles per (b,h)) at identical MFMA/softmax
// work — attacks the staging/latency cost that two micro-opts failed to
// hide.  Per-wave inner loop identical to the validated 4-wave version
// (each wave owns 16 Q rows; qrow0 = qt*128 + wave*16).
// (Round-8 L2-warmup prefetch measured -17us — removed.)
#define KSTR 136
#define VSTR 68
__global__ __launch_bounds__(512) void attn_part(
    const ushort* __restrict__ qkv, float* __restrict__ part_o,
    float* __restrict__ part_l, int T, int slots_bh) {
  const int S = 2048, LD = 6144;
  const int tid = threadIdx.x;
  const int wave = tid >> 6, lane = tid & 63;
  const int quad = lane >> 4, l16 = lane & 15;
  const int h = blockIdx.y;
  const int b = blockIdx.z;

  // decode (qt, chunk) from blockIdx.x, qt descending; 16 Q-tiles of 128.
  // tiles(qt) = 2*(qt+1) 64-key tiles; cnt(qt) = (2*qt+1)/T + 1
  int y = blockIdx.x, qt = -1, ch = 0;
  for (int q = 15; q >= 0; --q) {
    const int c = (2 * q + 1) / T + 1;
    if (qt < 0) {
      if (y < c) { qt = q; ch = y; } else y -= c;
    }
  }
  int sb = 0;
  for (int q = 0; q < qt; q++) sb += (2 * q + 1) / T + 1;
  const long slot = ((long)(b * 16 + h)) * slots_bh + sb + ch;

  const ushort* base = qkv + (long)b * S * LD;
  const int qrow0 = qt * 128 + wave * 16;
  const int kb0 = ch * T * 64;
  const int kbend = min((ch + 1) * T * 64, qt * 128 + 128);

  __shared__ ushort Ks[64 * KSTR];
  __shared__ ushort Vs[128 * VSTR];
  __shared__ ushort Ps[8][16 * VSTR];

  // Q fragments (A-layout)
  bf16x8 qf[4];
  {
    const ushort* qp = base + (long)(qrow0 + l16) * LD + h * 128 + quad * 8;
#pragma unroll
    for (int c = 0; c < 4; c++) qf[c] = *(const bf16x8*)(qp + c * 32);
  }

  float l_lane[4] = {0.f, 0.f, 0.f, 0.f};
  f32x4 o[8];
#pragma unroll
  for (int f = 0; f < 8; f++) o[f] = (f32x4){0.f, 0.f, 0.f, 0.f};

  const float scale = 0.08838834764831845f;  // 1/sqrt(128)

  // staging maps (512 threads)
  const int k_row = tid >> 4;          // 0..31, 2 passes (+0,+32)
  const int k_dcol = (tid & 15) * 8;
  const int v_key2 = (tid & 31) * 2;   // key pair
  const int v_dc0 = tid >> 5;          // 0..15, single pass

  for (int kb = kb0; kb < kbend; kb += 64) {
    __syncthreads();   // prior-iter LDS reads done
    // stage K [64][128]: 2 passes x 512 threads x 16B
#pragma unroll
    for (int it = 0; it < 2; it++) {
      const int row = k_row + it * 32;
      *(uint4*)&Ks[row * KSTR + k_dcol] =
          *(const uint4*)(base + (long)(kb + row) * LD + 2048 + h * 128 + k_dcol);
    }
    // stage V transposed [d][key], packed pair writes: 1 pass
    {
      const ushort* vg = base + (long)(kb + v_key2) * LD + 4096 + h * 128 + v_dc0 * 8;
      ushort va[8] __attribute__((aligned(16)));
      ushort vb[8] __attribute__((aligned(16)));
      *(uint4*)va = *(const uint4*)vg;
      *(uint4*)vb = *(const uint4*)(vg + LD);
#pragma unroll
      for (int e = 0; e < 8; e++) {
        const uint32_t pk = (uint32_t)va[e] | ((uint32_t)vb[e] << 16);
        *(uint32_t*)&Vs[(v_dc0 * 8 + e) * VSTR + v_key2] = pk;
      }
    }
    __syncthreads();

    // wave-uniform live sub-tile count (diagonal region only)
    int nkt = (qrow0 + 15 - kb) / 16 + 1;
    if (nkt > 4) nkt = 4;

    // S = Q K^T
    f32x4 sc[4] = {};
#pragma unroll
    for (int kt = 0; kt < 4; kt++) {
      if (kt < nkt) {
#pragma unroll
        for (int c = 0; c < 4; c++) {
          bf16x8 kf = *(const bf16x8*)&Ks[(kt * 16 + l16) * KSTR + c * 32 + quad * 8];
          sc[kt] = mfma16(qf[c], kf, sc[kt]);
        }
      }
    }

    // unnormalized exp + causal mask
#pragma unroll
    for (int r = 0; r < 4; r++) {
      const int qpos = qrow0 + quad * 4 + r;
      const int prow = (quad * 4 + r) * VSTR;
      float psum = 0.f;
#pragma unroll
      for (int kt = 0; kt < 4; kt++) {
        const float e = __expf(sc[kt][r] * scale);
        const float p = (kb + kt * 16 + l16 > qpos) ? 0.f : e;
        psum += p;
        Ps[wave][prow + kt * 16 + l16] = f2bf(p);
      }
      l_lane[r] += psum;
    }

    // PV
    bf16x8 pf0 = *(const bf16x8*)&Ps[wave][l16 * VSTR + quad * 8];
#pragma unroll
    for (int f = 0; f < 8; f++) {
      bf16x8 vf0 = *(const bf16x8*)&Vs[(f * 16 + l16) * VSTR + quad * 8];
      o[f] = mfma16(pf0, vf0, o[f]);
    }
    if (nkt > 2) {
      bf16x8 pf1 = *(const bf16x8*)&Ps[wave][l16 * VSTR + 32 + quad * 8];
#pragma unroll
      for (int f = 0; f < 8; f++) {
        bf16x8 vf1 = *(const bf16x8*)&Vs[(f * 16 + l16) * VSTR + 32 + quad * 8];
        o[f] = mfma16(pf1, vf1, o[f]);
      }
    }
  }

  // write partials: o rows are wave*16 + quad*4 + r (0..127), cols f*16+l16
  float* po = part_o + slot * 16384;
#pragma unroll
  for (int r = 0; r < 4; r++) {
    float l = l_lane[r];
    l += __shfl_xor(l, 1);
    l += __shfl_xor(l, 2);
    l += __shfl_xor(l, 4);
    l += __shfl_xor(l, 8);
    const int row = wave * 16 + quad * 4 + r;
#pragma unroll
    for (int f = 0; f < 8; f++)
      po[row * 128 + f * 16 + l16] = o[f][r];
    if (l16 == 0) part_l[slot * 128 + row] = l;
  }
}

// ---------- merge partials -> attnb (bf16), 128-row Q tiles ----------
__global__ __launch_bounds__(256) void attn_merge(
    const float* __restrict__ part_o, const float* __restrict__ part_l,
    ushort* __restrict__ attnb, int T, int slots_bh) {
  const int qt = blockIdx.x, h = blockIdx.y, b = blockIdx.z;
  const int tid = threadIdx.x;
  const int cnt = (2 * qt + 1) / T + 1;
  int sb = 0;
  for (int q = 0; q < qt; q++) sb += (2 * q + 1) / T + 1;
  const long slot0 = ((long)(b * 16 + h)) * slots_bh + sb;

  for (int e4 = tid; e4 < 4096; e4 += 256) {   // float4 index within 128x128
    const int elem = e4 * 4;
    const int row = elem >> 7;
    const int d = elem & 127;
    float4 s = {0.f, 0.f, 0.f, 0.f};
    float l = 0.f;
    for (int c = 0; c < cnt; c++) {
      const float4 p = *(const float4*)&part_o[(slot0 + c) * 16384 + elem];
      s.x += p.x; s.y += p.y; s.z += p.z; s.w += p.w;
      l += part_l[(slot0 + c) * 128 + row];
    }
    const float inv = 1.0f / l;
    ushort4 ov;
    ov.x = f2bf(s.x * inv); ov.y = f2bf(s.y * inv);
    ov.z = f2bf(s.z * inv); ov.w = f2bf(s.w * inv);
    *(ushort4*)&attnb[((long)b * 2048 + qt * 128 + row) * 2048 + h * 128 + d] = ov;
  }
}

// ---------- launch ----------
static const void* find_by_size(void* const* d_in, const int* in_sizes,
                                int n_in, long want) {
  for (int i = 0; i < n_in; i++)
    if ((long)in_sizes[i] == want) return d_in[i];
  return nullptr;
}

extern "C" void kernel_launch(void* const* d_in, const int* in_sizes, int n_in,
                              void* d_out, int out_size, void* d_ws, size_t ws_size,
                              hipStream_t stream) {
  const float* hidden = (const float*)find_by_size(d_in, in_sizes, n_in, 8388608);
  const float* Wqkv   = (const float*)find_by_size(d_in, in_sizes, n_in, 12582912);
  const float* bqkv   = (const float*)find_by_size(d_in, in_sizes, n_in, 6144);
  const float* Wo     = (const float*)find_by_size(d_in, in_sizes, n_in, 4194304);
  const float* bo     = (const float*)find_by_size(d_in, in_sizes, n_in, 2048);

  uintptr_t w = (uintptr_t)d_ws;
  ushort* hiddenB = (ushort*)w; w += (size_t)4096 * 2048 * 2;
  ushort* WqkvT   = (ushort*)w; w += (size_t)6144 * 2048 * 2;
  ushort* WoT     = (ushort*)w; w += (size_t)2048 * 2048 * 2;
  ushort* qkvb    = (ushort*)w; w += (size_t)4096 * 6144 * 2;
  ushort* attnb   = (ushort*)w; w += (size_t)4096 * 2048 * 2;
  float*  tab     = (float*)w;  w += (size_t)2048 * 64 * 2 * 4;
  const size_t fixed_bytes = w - (uintptr_t)d_ws;

  // choose T (iters of 64 keys per attn block): smallest that fits ws.
  // 16 Q-tiles of 128 rows; tiles(qt)=2(qt+1); cnt(qt)=(2qt+1)/T+1.
  int T = 8, slots_bh = 0;
  for (;; T *= 2) {
    slots_bh = 0;
    for (int q = 0; q < 16; q++) slots_bh += (2 * q + 1) / T + 1;
    const size_t need = fixed_bytes +
        (size_t)slots_bh * 32 * (16384 + 128) * 4;
    if (need <= ws_size || T >= 32) break;
  }
  float* part_o = (float*)w; w += (size_t)slots_bh * 32 * 16384 * 4;
  float* part_l = (float*)w; w += (size_t)slots_bh * 32 * 128 * 4;

  cast_f32_bf16<<<8192, 256, 0, stream>>>(hidden, hiddenB, 8388608L);
  transpose_cast<<<dim3(192, 64), 256, 0, stream>>>(Wqkv, WqkvT, 2048, 6144);
  transpose_cast<<<dim3(64, 64), 256, 0, stream>>>(Wo, WoT, 2048, 2048);
  rope_table<<<512, 256, 0, stream>>>(tab);
  // QKV: M=4096 N=6144 K=2048 -> 16x24 = 384 blocks (384%8==0)
  gemm256<false><<<dim3(384), 512, 0, stream>>>(hiddenB, WqkvT, bqkv,
                                                qkvb, 6144, 2048, 16);
  rope_apply<<<2048, 256, 0, stream>>>(qkvb, tab);
  attn_part<<<dim3(slots_bh, 16, 2), 512, 0, stream>>>(qkvb, part_o, part_l,
                                                       T, slots_bh);
  attn_merge<<<dim3(16, 16, 2), 256, 0, stream>>>(part_o, part_l, attnb,
                                                  T, slots_bh);
  // proj: M=4096 N=2048 K=2048 -> 16x8 = 128 blocks (128%8==0)
  gemm256<true><<<dim3(128), 512, 0, stream>>>(attnb, WoT, bo,
                                               d_out, 2048, 2048, 16);
}